// Round 7
// baseline (24934.210 us; speedup 1.0000x reference)
//
#include <hip/hip_runtime.h>

typedef unsigned short u16;
typedef unsigned int u32;
typedef unsigned long long u64;
typedef __attribute__((ext_vector_type(4))) float f32x4;
typedef __attribute__((ext_vector_type(8))) short short8;
typedef __attribute__((ext_vector_type(4))) short short4v;

__device__ __forceinline__ float bf2f(u16 v){ u32 b = ((u32)v)<<16; float f; __builtin_memcpy(&f,&b,4); return f; }
__device__ __forceinline__ u16 f2bf(float f){ u32 b; __builtin_memcpy(&b,&f,4); b = b + 0x7fffu + ((b>>16)&1u); return (u16)(b>>16); }
__device__ __forceinline__ float sigm(float x){ return 1.f/(1.f+__expf(-x)); }
__device__ __forceinline__ float tanh_a(float x){ return 1.f - 2.f/(__expf(2.f*x)+1.f); }

typedef const __attribute__((address_space(1))) u32* gas1;
typedef __attribute__((address_space(3))) u32* las3;
__device__ __forceinline__ void gld16(const u16* g, u16* l){
  __builtin_amdgcn_global_load_lds((gas1)g, (las3)l, 16, 0, 0);
}

// proven exchange primitives: relaxed agent-scope atomics (tags are ground truth)
__device__ __forceinline__ void pub64(u32* p, u64 v){
  __hip_atomic_store((u64*)p, v, __ATOMIC_RELAXED, __HIP_MEMORY_SCOPE_AGENT);
}
__device__ __forceinline__ void pub32(u32* p, u32 v){
  __hip_atomic_store(p, v, __ATOMIC_RELAXED, __HIP_MEMORY_SCOPE_AGENT);
}
__device__ __forceinline__ u64 pol64(const u32* p){
  return __hip_atomic_load((const u64*)p, __ATOMIC_RELAXED, __HIP_MEMORY_SCOPE_AGENT);
}
__device__ __forceinline__ u32 pol32(const u32* p){
  return __hip_atomic_load(p, __ATOMIC_RELAXED, __HIP_MEMORY_SCOPE_AGENT);
}

// raw workgroup barrier: LDS-ordering only — global stores/loads drain in background.
// Cross-WG ordering is carried by tag words, never by barriers. (rule #18: sched_barrier)
__device__ __forceinline__ void barx(){
  asm volatile("s_waitcnt lgkmcnt(0)" ::: "memory");
  __builtin_amdgcn_s_barrier();
  __builtin_amdgcn_sched_barrier(0);
}

// ---------------- pack / cast kernels ----------------
__global__ void cast_x_kernel(const float* __restrict__ in, u16* __restrict__ out){
  int i = blockIdx.x*256 + threadIdx.x;
  for (; i < 4194304; i += 2048*256){
    f32x4 v = ((const f32x4*)in)[i];
    int e = i*4;
    int b = e >> 19, t = (e >> 9) & 1023, k = e & 511;
    short4v o;
    o[0]=(short)f2bf(v[0]); o[1]=(short)f2bf(v[1]); o[2]=(short)f2bf(v[2]); o[3]=(short)f2bf(v[3]);
    *(short4v*)&out[(size_t)(t*32+b)*512 + k] = o;
  }
}

__global__ void pack_w_kernel(const float* __restrict__ w1, const float* __restrict__ wx, const float* __restrict__ wh,
                              u16* __restrict__ w1p, u16* __restrict__ wxwhp){
  int e = blockIdx.x*256 + threadIdx.x;
  for (; e < 7340032; e += 2048*256){
    if (e < 1048576){
      int h = e & 511, k = (e>>9)&511, g = e>>18;
      w1p[(size_t)(g*512+h)*512 + k] = f2bf(w1[(size_t)g*262144 + (size_t)k*512 + h]);
    } else {
      int r = e - 1048576;
      int lv = r >> 21;
      int q = r & 2097151;
      int n = q >> 10, k = q & 1023;
      int g = n >> 9, h = n & 511;
      float v;
      if (k < 512) v = wx[(size_t)lv*1048576 + (size_t)g*262144 + (size_t)k*512 + h];
      else         v = wh[(size_t)lv*1048576 + (size_t)g*262144 + (size_t)(k-512)*512 + h];
      wxwhp[(size_t)lv*2097152 + (size_t)n*1024 + k] = f2bf(v);
    }
  }
}

__global__ void cast_u_kernel(const float* __restrict__ u1, const float* __restrict__ uv,
                              u16* __restrict__ u1p, u16* __restrict__ uv0p){
  int e = blockIdx.x*256 + threadIdx.x;
  for (; e < 1835008; e += 1024*256){
    if (e < 1048576) u1p[e] = f2bf(u1[e]);
    else { int r = e - 1048576; uv0p[r] = f2bf(uv[(size_t)(r>>18)*1048576 + (r & 262143)]); }
  }
}

// ---------------- GEMM: pre1[tb,n] = xb @ w1p^T + b1 (proven) ----------------
__global__ __launch_bounds__(256) void gemm_pre_kernel(
    const u16* __restrict__ A1, const u16* __restrict__ B1,
    const float* __restrict__ bias, int bmask,
    u16* __restrict__ Out)
{
  __shared__ u16 As[128*64];
  __shared__ u16 Bs[128*64];
  const int tid = threadIdx.x;
  const int wv = tid>>6, lane = tid&63;
  const int l15 = lane&15, l4 = lane>>4;
  const int m0 = blockIdx.x*128, n0 = blockIdx.y*128;
  const int wm = wv>>1, wn = wv&1;
  f32x4 acc[4][4];
#pragma unroll
  for (int a=0;a<4;a++)
#pragma unroll
    for (int bq=0;bq<4;bq++) acc[a][bq] = (f32x4){0.f,0.f,0.f,0.f};

  for (int kt=0;kt<8;kt++){
    const int k0 = kt*64;
    __syncthreads();
#pragma unroll
    for (int i=0;i<4;i++){
      int chunk = wv*4 + i;
      int fb = chunk*1024 + lane*16;
      int row = fb>>7;
      int slot = (fb>>4)&7;
      const u16* srcA = A1 + (size_t)(m0+row)*512 + k0 + ((slot ^ (row&7))<<3);
      gld16(srcA, (u16*)As + chunk*512);
      const u16* srcB = B1 + (size_t)(n0+row)*512 + k0 + ((slot ^ (row&7))<<3);
      gld16(srcB, (u16*)Bs + chunk*512);
    }
    __syncthreads();
#pragma unroll
    for (int kk=0;kk<2;kk++){
      short8 af[4], bfq[4];
#pragma unroll
      for (int mi=0;mi<4;mi++){
        int row = wm*64 + mi*16 + l15;
        int s16 = l4 + kk*4;
        af[mi] = *(const short8*)&As[row*64 + ((s16 ^ (row&7))<<3)];
      }
#pragma unroll
      for (int ni=0;ni<4;ni++){
        int row = wn*64 + ni*16 + l15;
        int s16 = l4 + kk*4;
        bfq[ni] = *(const short8*)&Bs[row*64 + ((s16 ^ (row&7))<<3)];
      }
#pragma unroll
      for (int mi=0;mi<4;mi++)
#pragma unroll
        for (int ni=0;ni<4;ni++)
          acc[mi][ni] = __builtin_amdgcn_mfma_f32_16x16x32_bf16(af[mi], bfq[ni], acc[mi][ni], 0,0,0);
    }
  }
#pragma unroll
  for (int ni=0;ni<4;ni++){
    int col = n0 + wn*64 + ni*16 + l15;
    float bb = bias[col & bmask];
#pragma unroll
    for (int mi=0;mi<4;mi++){
#pragma unroll
      for (int i=0;i<4;i++){
        int row = m0 + wm*64 + mi*16 + l4*4 + i;
        Out[(size_t)row*2048 + col] = f2bf(acc[mi][ni][i] + bb);
      }
    }
  }
}

// ================ fused pipelined megakernel (62 active WGs, grid 128) ================
// role by (x=bid&7, r=bid>>3):
//   x==0, r<8 : scan0 gk=r        (8 WGs, 64 h-cols x 32 batches each)
//   x in 1..3, r<2 : scan layer l=x, ch=r (2 WGs/layer, 256 cols x 32 batches)
//   x in 4..6, r<16: pre cluster lv=x-4, cg=r (16 WGs/layer, 128 cols x 32 batches)
// flags: prog[0..7]=scan0; prog[8+lv*2+ch]=scan l; prog[16+lv*16+cg]=pre.
// rings: hring[l][64][32][512] u32 tagged; pring[lv][64][32][2048] u32 tagged.
__global__ __launch_bounds__(512,2) void mega_kernel(
    const u16* __restrict__ pre1, const u16* __restrict__ u1p,
    const u16* __restrict__ uv0p, const u16* __restrict__ xb,
    const u16* __restrict__ wxwhp, const float* __restrict__ bv,
    u32* hring, u32* pring, u32* prog, float* __restrict__ out)
{
  __shared__ char smem[66560];
  const int bid = blockIdx.x;
  const int x = bid & 7, rr_ = bid >> 3;
  const int tid = threadIdx.x;
  const int lane = tid&63, wv = tid>>6;
  const int l15 = lane&15, l4 = lane>>4;

  if (x == 0){
    if (rr_ >= 8) return;
    // ======== scan layer 0: gk=rr_, all 32 batches, 64 h-cols ========
    u16* hs = (u16*)smem;                 // [32][512] swizzled
    float* recb = (float*)(smem+32768);   // [32][256]
    const int gk = rr_, kb = gk*64;
    const int g = wv>>1, ch = wv&1;
    short8 bfr[2][16];
#pragma unroll
    for (int n=0;n<2;n++){
      const u16* up = u1p + (size_t)g*262144 + (kb + ch*32 + n*16 + l15);
#pragma unroll
      for (int s=0;s<16;s++){
        int kbase = s*32 + l4*8;
#pragma unroll
        for (int j=0;j<8;j++) bfr[n][s][j] = (short)up[(size_t)(kbase+j)*512];
      }
    }
    { short8 z = {0,0,0,0,0,0,0,0};
      for (int i=tid;i<2048;i+=512) ((short8*)hs)[i]=z; }
    const int b = tid>>4, q = tid&15;
    const int c0 = q*4;                   // own 4 local h-cols
    float cc[4] = {0.f,0.f,0.f,0.f};
    __syncthreads();

    for (int t=0;t<1024;++t){
      const u32 tag = (u32)(t+1);
      if ((t&15)==0 && t>=48){            // backpressure: pre-lv0 >= t-48
        int thr = t-48;
        if (tid<16){ while ((int)pol32(&prog[16+tid]) < thr) __builtin_amdgcn_s_sleep(8); }
        barx();
      }
      // pre1 plain loads (independent of h)
      const u16* prow = pre1 + (size_t)(t*32 + b)*2048 + kb + c0;
      u64 pw0 = *(const u64*)(prow);
      u64 pw1 = *(const u64*)(prow+512);
      u64 pw2 = *(const u64*)(prow+1024);
      u64 pw3 = *(const u64*)(prow+1536);
      // rec MFMA: 2 M-tiles x 2 N-tiles x 16 K
      f32x4 acc[2][2];
#pragma unroll
      for (int m=0;m<2;m++){ acc[m][0]=(f32x4){0,0,0,0}; acc[m][1]=(f32x4){0,0,0,0}; }
#pragma unroll
      for (int m=0;m<2;m++){
        int rb = (m*16+l15)*512, sw = (l15&7)<<3;
#pragma unroll
        for (int s=0;s<16;s++){
          short8 a = *(const short8*)&hs[rb + ((s*32 + l4*8) ^ sw)];
          acc[m][0] = __builtin_amdgcn_mfma_f32_16x16x32_bf16(a, bfr[0][s], acc[m][0], 0,0,0);
          acc[m][1] = __builtin_amdgcn_mfma_f32_16x16x32_bf16(a, bfr[1][s], acc[m][1], 0,0,0);
        }
      }
      {
        int base = g*64 + ch*32 + l15;
#pragma unroll
        for (int m=0;m<2;m++)
#pragma unroll
          for (int n=0;n<2;n++)
#pragma unroll
            for (int i=0;i<4;i++)
              recb[(m*16 + l4*4 + i)*256 + base + n*16] = acc[m][n][i];
      }
      barx();
      // gates: thread owns (b, 4 cols)
      u16 hb[4];
#pragma unroll
      for (int j=0;j<4;j++){
        float ri = recb[b*256 + c0 + j];
        float rf = recb[b*256 + 64 + c0 + j];
        float rg = recb[b*256 + 128 + c0 + j];
        float ro = recb[b*256 + 192 + c0 + j];
        float gi = sigm(bf2f((u16)(pw0>>(16*j))) + ri);
        float gf = sigm(bf2f((u16)(pw1>>(16*j))) + rf);
        float gg = sigm(bf2f((u16)(pw2>>(16*j))) + rg);
        float go = sigm(bf2f((u16)(pw3>>(16*j))) + ro);
        cc[j] = gf + cc[j] + gi*gg;
        hb[j] = f2bf(go + tanh_a(cc[j]));
      }
      u32* slot = hring + (size_t)(t&63)*16384 + (size_t)b*512;
      pub64(&slot[kb+c0],   (((u64)((tag<<16)|(u32)hb[1]))<<32) | (u64)((tag<<16)|(u32)hb[0]));
      pub64(&slot[kb+c0+2], (((u64)((tag<<16)|(u32)hb[3]))<<32) | (u64)((tag<<16)|(u32)hb[2]));
      const int swb = (b&7)<<3;
      *(u32*)&hs[b*512 + ((kb+c0)   ^ swb)] = (u32)hb[0] | ((u32)hb[1]<<16);
      *(u32*)&hs[b*512 + ((kb+c0+2) ^ swb)] = (u32)hb[2] | ((u32)hb[3]<<16);
      // all-to-all gather: 28 foreign cols (14 u64), batched tag-poll
      {
        u64 nv[14];
        for(;;){
#pragma unroll
          for (int j=0;j<14;j++){
            int fc = q*28 + 2*j;
            int ac = fc + (fc>=kb ? 64 : 0);
            nv[j] = pol64(&slot[ac]);
          }
          u32 ok = 1;
#pragma unroll
          for (int j=0;j<14;j++){
            if ((u32)(((u32)nv[j])>>16) != tag) ok=0;
            if ((u32)(nv[j]>>48) != tag) ok=0;
          }
          if (ok) break;
          __builtin_amdgcn_s_sleep(1);
        }
#pragma unroll
        for (int j=0;j<14;j++){
          int fc = q*28 + 2*j;
          int ac = fc + (fc>=kb ? 64 : 0);
          *(u32*)&hs[b*512 + (ac ^ swb)] = ((u32)nv[j]&0xffffu) | (((u32)(nv[j]>>32)&0xffffu)<<16);
        }
      }
      barx();
      if (tid==0) pub32(&prog[gk], tag);
    }
  } else if (x <= 3){
    if (rr_ >= 2) return;
    // ======== scan layers 1..3: l=x, ch=rr_, 256 cols x 32 batches ========
    u16* hs = (u16*)smem;
    float* recb = (float*)(smem+32768);
    const int l = x, lv = l-1, ch = rr_;
    const int cbase = ch*256;
    short8 bfr[2][16];
#pragma unroll
    for (int n=0;n<2;n++){
      const u16* up = uv0p + (size_t)lv*262144 + (cbase + wv*32 + n*16 + l15);
#pragma unroll
      for (int s=0;s<16;s++){
        int kbase = s*32 + l4*8;
#pragma unroll
        for (int j=0;j<8;j++) bfr[n][s][j] = (short)up[(size_t)(kbase+j)*512];
      }
    }
    { short8 z = {0,0,0,0,0,0,0,0};
      for (int i=tid;i<2048;i+=512) ((short8*)hs)[i]=z; }
    const int b = tid>>4, q = tid&15;
    const int oc = cbase + q*16;          // own 16 global cols
    float cv[16];
#pragma unroll
    for (int j=0;j<16;j++) cv[j]=0.f;
    u32* hr = hring + (size_t)l*1048576;
    u32* pr = pring + (size_t)lv*4194304;
    const int is_last = (l==3);
    __syncthreads();

    for (int t=0;t<1024;++t){
      const u32 tag = (u32)(t+1);
      if (l<3 && (t&15)==0 && t>=48){     // backpressure: pre-lv=l >= t-48
        int thr = t-48;
        if (tid<16){ while ((int)pol32(&prog[16 + l*16 + tid]) < thr) __builtin_amdgcn_s_sleep(8); }
        barx();
      }
      // forward edge: flag-first wait on pre-lv (16 producer flags)
      if (tid<16){ while ((int)pol32(&prog[16 + lv*16 + tid]) < (int)tag) __builtin_amdgcn_s_sleep(8); }
      barx();
      // issue pre reads (in flight under MFMA): 4 gates x 16 cols = 32 u64
      const u32* ps = pr + (size_t)(t&63)*65536 + (size_t)b*2048;
      u64 pv[32];
#pragma unroll
      for (int g4=0;g4<4;g4++)
#pragma unroll
        for (int j=0;j<8;j++)
          pv[g4*8+j] = pol64(&ps[g4*512 + oc + 2*j]);
      // rec MFMA
      f32x4 acc[2][2];
#pragma unroll
      for (int m=0;m<2;m++){ acc[m][0]=(f32x4){0,0,0,0}; acc[m][1]=(f32x4){0,0,0,0}; }
#pragma unroll
      for (int m=0;m<2;m++){
        int rb = (m*16+l15)*512, sw = (l15&7)<<3;
#pragma unroll
        for (int s=0;s<16;s++){
          short8 a = *(const short8*)&hs[rb + ((s*32 + l4*8) ^ sw)];
          acc[m][0] = __builtin_amdgcn_mfma_f32_16x16x32_bf16(a, bfr[0][s], acc[m][0], 0,0,0);
          acc[m][1] = __builtin_amdgcn_mfma_f32_16x16x32_bf16(a, bfr[1][s], acc[m][1], 0,0,0);
        }
      }
      {
        int base = wv*32 + l15;
#pragma unroll
        for (int m=0;m<2;m++)
#pragma unroll
          for (int n=0;n<2;n++)
#pragma unroll
            for (int i=0;i<4;i++)
              recb[(m*16 + l4*4 + i)*256 + base + n*16] = acc[m][n][i];
      }
      // verify pre tags (rare retry; flag already passed)
      for(;;){
        u32 ok=1;
#pragma unroll
        for (int i=0;i<32;i++){
          if ((u32)(((u32)pv[i])>>16) != tag) ok=0;
          if ((u32)(pv[i]>>48) != tag) ok=0;
        }
        if (ok) break;
        __builtin_amdgcn_s_sleep(2);
#pragma unroll
        for (int g4=0;g4<4;g4++)
#pragma unroll
          for (int j=0;j<8;j++)
            pv[g4*8+j] = pol64(&ps[g4*512 + oc + 2*j]);
      }
      barx();
      // gates (shared rec across 4 gates — faithful to source bug)
      u16 hb[16]; float hf[16];
#pragma unroll
      for (int j=0;j<16;j++){
        float rv = recb[b*256 + q*16 + j];
        u32 w0 = (u32)(pv[(j>>1)]      >> (32*(j&1)));
        u32 w1v= (u32)(pv[8+(j>>1)]    >> (32*(j&1)));
        u32 w2 = (u32)(pv[16+(j>>1)]   >> (32*(j&1)));
        u32 w3 = (u32)(pv[24+(j>>1)]   >> (32*(j&1)));
        float gi = sigm(bf2f((u16)w0) + rv);
        float gf = sigm(bf2f((u16)w1v) + rv);
        float gg = sigm(bf2f((u16)w2) + rv);
        float go = sigm(bf2f((u16)w3) + rv);
        cv[j] = gf + cv[j] + gi*gg;
        float h = go + tanh_a(cv[j]);
        hb[j] = f2bf(h); hf[j] = h;
      }
      u32* hslot = hr + (size_t)(t&63)*16384 + (size_t)b*512;
#pragma unroll
      for (int jj=0;jj<8;jj++){
        u64 m = (((u64)((tag<<16)|(u32)hb[2*jj+1]))<<32) | (u64)((tag<<16)|(u32)hb[2*jj]);
        pub64(&hslot[oc + 2*jj], m);
      }
      const int swb = (b&7)<<3;
#pragma unroll
      for (int jh=0;jh<2;jh++){
        short8 hv8;
#pragma unroll
        for (int i=0;i<8;i++) hv8[i] = (short)hb[jh*8+i];
        *(short8*)&hs[b*512 + ((oc + jh*8) ^ swb)] = hv8;
      }
      if (is_last){
#pragma unroll
        for (int jq=0;jq<4;jq++){
          f32x4 h4 = {hf[jq*4],hf[jq*4+1],hf[jq*4+2],hf[jq*4+3]};
          *(f32x4*)&out[32768 + ((size_t)(b*1024+t))*512 + oc + jq*4] = h4;
        }
        if (t==1023){
#pragma unroll
          for (int jq=0;jq<4;jq++){
            f32x4 h4 = {hf[jq*4],hf[jq*4+1],hf[jq*4+2],hf[jq*4+3]};
            f32x4 c4 = {cv[jq*4],cv[jq*4+1],cv[jq*4+2],cv[jq*4+3]};
            *(f32x4*)&out[(size_t)b*512 + oc + jq*4] = h4;
            *(f32x4*)&out[16384 + (size_t)b*512 + oc + jq*4] = c4;
          }
        }
      }
      // partner gather (cyclic edge: pure tag-poll)
      {
        const int pc = (ch^1)*256 + q*16;
        const u32* src = hslot + pc;
        u64 nv[8];
        for(;;){
#pragma unroll
          for (int j=0;j<8;j++) nv[j] = pol64(&src[2*j]);
          u32 ok=1;
#pragma unroll
          for (int j=0;j<8;j++){
            if ((u32)(((u32)nv[j])>>16)!=tag) ok=0;
            if ((u32)(nv[j]>>48)!=tag) ok=0;
          }
          if (ok) break;
          __builtin_amdgcn_s_sleep(1);
        }
#pragma unroll
        for (int jh=0;jh<2;jh++){
          short8 hh;
#pragma unroll
          for (int i=0;i<4;i++){
            hh[2*i]   = (short)(u16)(nv[jh*4+i] & 0xffffu);
            hh[2*i+1] = (short)(u16)((nv[jh*4+i]>>32) & 0xffffu);
          }
          *(short8*)&hs[b*512 + ((pc + jh*8) ^ swb)] = hh;
        }
      }
      barx();
      if (tid==0) pub32(&prog[8 + lv*2 + ch], tag);
    }
  } else if (x <= 6){
    if (rr_ >= 16) return;
    // ======== pre cluster: lv=x-4, cg=rr_, 128 cols x 32 batches ========
    u16* hstage = (u16*)smem;             // [32][520]
    const int lv = x-4, cg = rr_;
    const int c = cg*128 + wv*16 + l15;
    const u16* Bw = wxwhp + (size_t)lv*2097152 + (size_t)c*1024;
    short8 bfr[32];
#pragma unroll
    for (int s=0;s<32;s++) bfr[s] = *(const short8*)&Bw[s*32 + l4*8];
    const float bias = bv[lv*2048 + (c & 511)];
    const int pb = tid>>4, pq = tid&15;   // poll: batch pb, cols pq*32..+31
    const u32* hrb = hring + (size_t)lv*1048576;
    u32* prb = pring + (size_t)lv*4194304;

    for (int t=0;t<1024;++t){
      const u32 tag = (u32)(t+1);
      if ((t&15)==0 && t>=48){            // backpressure: scan l=lv+1 >= t-48
        int thr = t-48;
        if (tid<2){ while ((int)pol32(&prog[8 + lv*2 + tid]) < thr) __builtin_amdgcn_s_sleep(8); }
        barx();
      }
      // forward edge: flag-first wait on h producers
      if (lv==0){
        if (tid<8){ while ((int)pol32(&prog[tid]) < (int)tag) __builtin_amdgcn_s_sleep(8); }
      } else {
        if (tid<2){ while ((int)pol32(&prog[8 + (lv-1)*2 + tid]) < (int)tag) __builtin_amdgcn_s_sleep(8); }
      }
      barx();
      // issue h bulk read (in flight under x-MFMA)
      const u32* hsrc = hrb + (size_t)(t&63)*16384 + (size_t)pb*512 + pq*32;
      u64 nv[16];
#pragma unroll
      for (int j=0;j<16;j++) nv[j] = pol64(&hsrc[2*j]);
      // x-part MFMA
      f32x4 acc[2] = {(f32x4){0,0,0,0},(f32x4){0,0,0,0}};
#pragma unroll
      for (int m=0;m<2;m++){
        const u16* xrow = xb + (size_t)(t*32 + m*16 + l15)*512;
#pragma unroll
        for (int s=0;s<16;s++){
          short8 a = *(const short8*)&xrow[s*32 + l4*8];
          acc[m] = __builtin_amdgcn_mfma_f32_16x16x32_bf16(a, bfr[s], acc[m], 0,0,0);
        }
      }
      // verify tags (rare retry)
      for(;;){
        u32 ok=1;
#pragma unroll
        for (int j=0;j<16;j++){
          if ((u32)(((u32)nv[j])>>16)!=tag) ok=0;
          if ((u32)(nv[j]>>48)!=tag) ok=0;
        }
        if (ok) break;
        __builtin_amdgcn_s_sleep(2);
#pragma unroll
        for (int j=0;j<16;j++) nv[j] = pol64(&hsrc[2*j]);
      }
#pragma unroll
      for (int j=0;j<16;j++){
        u32 pair = ((u32)nv[j]&0xffffu) | (((u32)(nv[j]>>32)&0xffffu)<<16);
        *(u32*)&hstage[pb*520 + pq*32 + 2*j] = pair;
      }
      barx();
      // h-part MFMA
#pragma unroll
      for (int m=0;m<2;m++){
        int arow = (m*16+l15)*520;
#pragma unroll
        for (int s=0;s<16;s++){
          short8 a = *(const short8*)&hstage[arow + s*32 + l4*8];
          acc[m] = __builtin_amdgcn_mfma_f32_16x16x32_bf16(a, bfr[16+s], acc[m], 0,0,0);
        }
      }
      // publish tagged pre
      u32* dst = prb + (size_t)(t&63)*65536 + c;
#pragma unroll
      for (int m=0;m<2;m++)
#pragma unroll
        for (int i=0;i<4;i++){
          u32 v = ((u32)f2bf(acc[m][i]+bias)) | (tag<<16);
          pub32(&dst[(size_t)(m*16 + l4*4 + i)*2048], v);
        }
      barx();
      if (tid==0) pub32(&prog[16 + lv*16 + cg], tag);
    }
  }
}

extern "C" void kernel_launch(void* const* d_in, const int* in_sizes, int n_in,
                              void* d_out, int out_size, void* d_ws, size_t ws_size,
                              hipStream_t stream)
{
  const float* x  = (const float*)d_in[0];
  const float* w1 = (const float*)d_in[1];
  const float* u1 = (const float*)d_in[2];
  const float* b1 = (const float*)d_in[3];
  const float* wx = (const float*)d_in[4];
  const float* wh = (const float*)d_in[5];
  const float* uv = (const float*)d_in[6];
  const float* bv = (const float*)d_in[7];
  float* out = (float*)d_out;

  char* p = (char*)d_ws;
  u16* pre1  = (u16*)p; p += (size_t)134217728;  // [1024*32][2048] bf16, rows t*32+b
  u16* xb    = (u16*)p; p += 33554432;           // [1024][32][512] bf16
  u16* w1p   = (u16*)p; p += 2097152;
  u16* wxwhp = (u16*)p; p += 12582912;           // 3 x [2048][1024] bf16
  u16* u1p   = (u16*)p; p += 2097152;
  u16* uv0p  = (u16*)p; p += 1572864;
  u32* hring = (u32*)p; p += 16777216;           // 4 x [64][32][512] u32
  u32* pring = (u32*)p; p += 50331648;           // 3 x [64][32][2048] u32
  u32* prog  = (u32*)p; p += 1024;
  if ((size_t)(p - (char*)d_ws) > ws_size) return;

  hipMemsetAsync(hring, 0, 16777216, stream);
  hipMemsetAsync(pring, 0, 50331648, stream);
  hipMemsetAsync(prog, 0, 1024, stream);
  cast_x_kernel<<<2048,256,0,stream>>>(x, xb);
  pack_w_kernel<<<2048,256,0,stream>>>(w1, wx, wh, w1p, wxwhp);
  cast_u_kernel<<<1024,256,0,stream>>>(u1, uv, u1p, uv0p);

  gemm_pre_kernel<<<dim3(256,16),256,0,stream>>>(xb, w1p, b1, 2047, pre1);
  mega_kernel<<<128,512,0,stream>>>(pre1, u1p, uv0p, xb, wxwhp, bv, hring, pring, prog, out);
}

// Round 8
// 7424.457 us; speedup vs baseline: 3.3584x; 3.3584x over previous
//
#include <hip/hip_runtime.h>

typedef unsigned short u16;
typedef unsigned int u32;
typedef unsigned long long u64;
typedef __attribute__((ext_vector_type(4))) float f32x4;
typedef __attribute__((ext_vector_type(8))) short short8;
typedef __attribute__((ext_vector_type(4))) short short4v;

__device__ __forceinline__ float bf2f(u16 v){ u32 b = ((u32)v)<<16; float f; __builtin_memcpy(&f,&b,4); return f; }
__device__ __forceinline__ u16 f2bf(float f){ u32 b; __builtin_memcpy(&b,&f,4); b = b + 0x7fffu + ((b>>16)&1u); return (u16)(b>>16); }
__device__ __forceinline__ float sigm(float x){ return 1.f/(1.f+__expf(-x)); }
__device__ __forceinline__ float tanh_a(float x){ return 1.f - 2.f/(__expf(2.f*x)+1.f); }
__device__ __forceinline__ int imin(int a, int b){ return a<b?a:b; }

typedef const __attribute__((address_space(1))) u32* gas1;
typedef __attribute__((address_space(3))) u32* las3;
__device__ __forceinline__ void gld16(const u16* g, u16* l){
  __builtin_amdgcn_global_load_lds((gas1)g, (las3)l, 16, 0, 0);
}

// ---- proven exchange primitives: HIP relaxed agent-scope atomics ----
__device__ __forceinline__ void pub64(u32* p, u64 v){
  __hip_atomic_store((u64*)p, v, __ATOMIC_RELAXED, __HIP_MEMORY_SCOPE_AGENT);
}
__device__ __forceinline__ void pub32(u32* p, u32 v){
  __hip_atomic_store(p, v, __ATOMIC_RELAXED, __HIP_MEMORY_SCOPE_AGENT);
}
__device__ __forceinline__ u64 pol64(const u32* p){
  return __hip_atomic_load((const u64*)p, __ATOMIC_RELAXED, __HIP_MEMORY_SCOPE_AGENT);
}
__device__ __forceinline__ u32 pol32(const u32* p){
  return __hip_atomic_load(p, __ATOMIC_RELAXED, __HIP_MEMORY_SCOPE_AGENT);
}

// raw workgroup barrier: LDS-ordering only (lgkmcnt covers DS and flat exchange ops).
// Plain global stores (out/hv_out) drain in BACKGROUND — not before the barrier.
// Cross-WG ordering is carried by tag words, never by barriers. rule #18: sched_barrier.
__device__ __forceinline__ void barx(){
  asm volatile("s_waitcnt lgkmcnt(0)" ::: "memory");
  __builtin_amdgcn_s_barrier();
  __builtin_amdgcn_sched_barrier(0);
}

// ---------------- pack / cast kernels ----------------
// xb layout: [t][b][512]
__global__ void cast_x_kernel(const float* __restrict__ in, u16* __restrict__ out){
  int i = blockIdx.x*256 + threadIdx.x;
  for (; i < 4194304; i += 2048*256){
    f32x4 v = ((const f32x4*)in)[i];
    int e = i*4;
    int b = e >> 19, t = (e >> 9) & 1023, k = e & 511;
    short4v o;
    o[0]=(short)f2bf(v[0]); o[1]=(short)f2bf(v[1]); o[2]=(short)f2bf(v[2]); o[3]=(short)f2bf(v[3]);
    *(short4v*)&out[(size_t)(t*32+b)*512 + k] = o;
  }
}

__global__ void pack_w_kernel(const float* __restrict__ w1, const float* __restrict__ wx, const float* __restrict__ wh,
                              u16* __restrict__ w1p, u16* __restrict__ wxwhp){
  int e = blockIdx.x*256 + threadIdx.x;
  for (; e < 7340032; e += 2048*256){
    if (e < 1048576){
      int h = e & 511, k = (e>>9)&511, g = e>>18;
      w1p[(size_t)(g*512+h)*512 + k] = f2bf(w1[(size_t)g*262144 + (size_t)k*512 + h]);
    } else {
      int r = e - 1048576;
      int lv = r >> 21;
      int q = r & 2097151;
      int n = q >> 10, k = q & 1023;
      int g = n >> 9, h = n & 511;
      float v;
      if (k < 512) v = wx[(size_t)lv*1048576 + (size_t)g*262144 + (size_t)k*512 + h];
      else         v = wh[(size_t)lv*1048576 + (size_t)g*262144 + (size_t)(k-512)*512 + h];
      wxwhp[(size_t)lv*2097152 + (size_t)n*1024 + k] = f2bf(v);
    }
  }
}

__global__ void cast_u_kernel(const float* __restrict__ u1, const float* __restrict__ uv,
                              u16* __restrict__ u1p, u16* __restrict__ uv0p){
  int e = blockIdx.x*256 + threadIdx.x;
  for (; e < 1835008; e += 1024*256){
    if (e < 1048576) u1p[e] = f2bf(u1[e]);
    else { int r = e - 1048576; uv0p[r] = f2bf(uv[(size_t)(r>>18)*1048576 + (r & 262143)]); }
  }
}

// ---------------- GEMM: pre1[tb,n] = xb @ w1p^T + b1 (rows are t*32+b) ----------------
__global__ __launch_bounds__(256) void gemm_pre_kernel(
    const u16* __restrict__ A1, const u16* __restrict__ B1,
    const float* __restrict__ bias, int bmask,
    u16* __restrict__ Out)
{
  __shared__ u16 As[128*64];
  __shared__ u16 Bs[128*64];
  const int tid = threadIdx.x;
  const int w = tid>>6, lane = tid&63;
  const int l15 = lane&15, l4 = lane>>4;
  const int m0 = blockIdx.x*128, n0 = blockIdx.y*128;
  const int wm = w>>1, wn = w&1;
  f32x4 acc[4][4];
#pragma unroll
  for (int a=0;a<4;a++)
#pragma unroll
    for (int bq=0;bq<4;bq++) acc[a][bq] = (f32x4){0.f,0.f,0.f,0.f};

  for (int kt=0;kt<8;kt++){
    const int k0 = kt*64;
    __syncthreads();
#pragma unroll
    for (int i=0;i<4;i++){
      int chunk = w*4 + i;
      int fb = chunk*1024 + lane*16;
      int row = fb>>7;
      int slot = (fb>>4)&7;
      const u16* srcA = A1 + (size_t)(m0+row)*512 + k0 + ((slot ^ (row&7))<<3);
      gld16(srcA, (u16*)As + chunk*512);
      const u16* srcB = B1 + (size_t)(n0+row)*512 + k0 + ((slot ^ (row&7))<<3);
      gld16(srcB, (u16*)Bs + chunk*512);
    }
    __syncthreads();
#pragma unroll
    for (int kk=0;kk<2;kk++){
      short8 af[4], bfq[4];
#pragma unroll
      for (int mi=0;mi<4;mi++){
        int row = wm*64 + mi*16 + l15;
        int s16 = l4 + kk*4;
        af[mi] = *(const short8*)&As[row*64 + ((s16 ^ (row&7))<<3)];
      }
#pragma unroll
      for (int ni=0;ni<4;ni++){
        int row = wn*64 + ni*16 + l15;
        int s16 = l4 + kk*4;
        bfq[ni] = *(const short8*)&Bs[row*64 + ((s16 ^ (row&7))<<3)];
      }
#pragma unroll
      for (int mi=0;mi<4;mi++)
#pragma unroll
        for (int ni=0;ni<4;ni++)
          acc[mi][ni] = __builtin_amdgcn_mfma_f32_16x16x32_bf16(af[mi], bfq[ni], acc[mi][ni], 0,0,0);
    }
  }
#pragma unroll
  for (int ni=0;ni<4;ni++){
    int col = n0 + wn*64 + ni*16 + l15;
    float bb = bias[col & bmask];
#pragma unroll
    for (int mi=0;mi<4;mi++){
#pragma unroll
      for (int i=0;i<4;i++){
        int row = m0 + wm*64 + mi*16 + l4*4 + i;
        Out[(size_t)row*2048 + col] = f2bf(acc[mi][ni][i] + bb);
      }
    }
  }
}

// ================ fused pipelined megakernel (round-6 structure, barx barriers) ================
// blocks 0..15   : scan layer 0 ; 16..27: scan layers 1..3 ; 28..123: pre clusters
// prog[0..11]: scan1-3 step flags; prog[32..47]: scan0 step flags;
// prog[64..159]: pre flags [lv*32 + r]. Flags gate RETRY paths only (tags stay truth).
__global__ __launch_bounds__(512,2) void mega_kernel(
    const u16* __restrict__ pre1, const u16* __restrict__ u1p,
    const u16* __restrict__ uv0p, const u16* __restrict__ xb,
    const u16* __restrict__ wxwhp, const float* __restrict__ bv,
    u32* hring, u32* pring, u32* prog, float* __restrict__ out)
{
  __shared__ char smem[33024];
  const int bid = blockIdx.x;
  const int tid = threadIdx.x;
  const int lane = tid&63, w = tid>>6;
  const int l15 = lane&15, l4 = lane>>4;

  if (bid < 16){
    // ======== scan layer 0 ========
    u16* hs = (u16*)smem;
    float* recb = (float*)(smem+16384);
    const int gk = bid & 7, gb = bid >> 3;
    const int b0 = gb*16, kb = gk*64;
    const int g = w>>1, ch = w&1;
    short8 bfr[2][16];
#pragma unroll
    for (int n=0;n<2;n++){
      const u16* up = u1p + (size_t)g*262144 + (kb + ch*32 + n*16 + l15);
#pragma unroll
      for (int s=0;s<16;s++){
        int kbase = s*32 + l4*8;
#pragma unroll
        for (int j=0;j<8;j++) bfr[n][s][j] = (short)up[(size_t)(kbase+j)*512];
      }
    }
    { short8 z = {0,0,0,0,0,0,0,0};
      for (int i=tid;i<1024;i+=512) ((short8*)hs)[i]=z; }
    const int b = tid>>5, q = tid&31;
    const int hc2 = q*2;
    float cA=0.f, cB=0.f;
    __syncthreads();

    for (int t=0;t<1024;++t){
      if ((t&15)==0 && t>=32){
        int thr = t-32;
        for(;;){
          int m0=(int)pol32(&prog[0]); m0=imin(m0,(int)pol32(&prog[1]));
          m0=imin(m0,(int)pol32(&prog[2])); m0=imin(m0,(int)pol32(&prog[3]));
          if (m0>=thr) break;
          __builtin_amdgcn_s_sleep(8);
        }
      }
      const u16* prow = pre1 + ((size_t)(t*32 + b0 + b))*2048 + kb + hc2;
      u32 pw0 = *(const u32*)(prow);
      u32 pw1 = *(const u32*)(prow+512);
      u32 pw2 = *(const u32*)(prow+1024);
      u32 pw3 = *(const u32*)(prow+1536);
      f32x4 acc0 = {0.f,0.f,0.f,0.f}, acc1 = {0.f,0.f,0.f,0.f};
      {
        int rb = l15*512, sw = (l15&7)<<3;
#pragma unroll
        for (int s=0;s<16;s++){
          short8 a = *(const short8*)&hs[rb + ((s*32 + l4*8) ^ sw)];
          acc0 = __builtin_amdgcn_mfma_f32_16x16x32_bf16(a, bfr[0][s], acc0, 0,0,0);
          acc1 = __builtin_amdgcn_mfma_f32_16x16x32_bf16(a, bfr[1][s], acc1, 0,0,0);
        }
      }
      {
        int base = g*64 + ch*32 + l15;
#pragma unroll
        for (int i=0;i<4;i++){
          recb[(l4*4+i)*256 + base]      = acc0[i];
          recb[(l4*4+i)*256 + base + 16] = acc1[i];
        }
      }
      barx();
      float ri0 = recb[b*256 + hc2],       ri1 = recb[b*256 + hc2+1];
      float rf0 = recb[b*256 + 64 + hc2],  rf1 = recb[b*256 + 64 + hc2+1];
      float rg0 = recb[b*256 + 128 + hc2], rg1 = recb[b*256 + 128 + hc2+1];
      float ro0 = recb[b*256 + 192 + hc2], ro1 = recb[b*256 + 192 + hc2+1];
      float gi0 = sigm(bf2f((u16)(pw0&0xffffu)) + ri0), gi1 = sigm(bf2f((u16)(pw0>>16)) + ri1);
      float gf0 = sigm(bf2f((u16)(pw1&0xffffu)) + rf0), gf1 = sigm(bf2f((u16)(pw1>>16)) + rf1);
      float gg0 = sigm(bf2f((u16)(pw2&0xffffu)) + rg0), gg1 = sigm(bf2f((u16)(pw2>>16)) + rg1);
      float go0 = sigm(bf2f((u16)(pw3&0xffffu)) + ro0), go1 = sigm(bf2f((u16)(pw3>>16)) + ro1);
      cA = gf0 + cA + gi0*gg0; float h0v = go0 + tanh_a(cA);
      cB = gf1 + cB + gi1*gg1; float h1v = go1 + tanh_a(cB);
      u16 hb0 = f2bf(h0v), hb1 = f2bf(h1v);
      const u32 tag = (u32)(t+1);
      u32* slot = hring + (size_t)(t&63)*16384;
      u64 msg = (((u64)((tag<<16)|(u32)hb1))<<32) | (u64)((tag<<16)|(u32)hb0);
      pub64(&slot[(size_t)(b0+b)*512 + kb + hc2], msg);
      u32 hpair = (u32)hb0 | ((u32)hb1<<16);
      *(u32*)&hs[b*512 + ((kb+hc2) ^ ((b&7)<<3))] = hpair;
      // gather 448 foreign cols (cyclic edge: pure tag-poll)
      {
        const u32* srcg = slot + (size_t)(b0+b)*512;
        u64 nv[7];
        for(;;){
#pragma unroll
          for (int j=0;j<7;j++){
            int fc = q*14 + 2*j;
            int ac = fc + (fc>=kb ? 64 : 0);
            nv[j] = pol64(&srcg[ac]);
          }
          u32 ok = 1;
#pragma unroll
          for (int j=0;j<7;j++){
            if ((u32)(((u32)nv[j])>>16) != tag) ok=0;
            if ((u32)(nv[j]>>48) != tag) ok=0;
          }
          if (ok) break;
          __builtin_amdgcn_s_sleep(1);
        }
#pragma unroll
        for (int j=0;j<7;j++){
          int fc = q*14 + 2*j;
          int ac = fc + (fc>=kb ? 64 : 0);
          u32 pair = ((u32)nv[j]&0xffffu) | ((u32)((nv[j]>>32)&0xffffu)<<16);
          *(u32*)&hs[b*512 + (ac ^ ((b&7)<<3))] = pair;
        }
      }
      barx();
      if (tid==0) pub32(&prog[32+bid], (u32)(t+1));
    }
  } else if (bid < 28){
    // ======== scan layers 1..3 ========
    u16* hs = (u16*)smem;
    float* recb = (float*)(smem+16384);
    const int l = 1 + ((bid-16)>>2);
    const int lv = l-1;
    const int sub = (bid-16)&3;
    const int ch = sub&1, gb = sub>>1;
    const int b0 = gb*16, cbase = ch*256;
    short8 bfr[2][16];
#pragma unroll
    for (int n=0;n<2;n++){
      const u16* up = uv0p + (size_t)lv*262144 + (cbase + w*32 + n*16 + l15);
#pragma unroll
      for (int s=0;s<16;s++){
        int kbase = s*32 + l4*8;
#pragma unroll
        for (int j=0;j<8;j++) bfr[n][s][j] = (short)up[(size_t)(kbase+j)*512];
      }
    }
    { short8 z = {0,0,0,0,0,0,0,0};
      for (int i=tid;i<1024;i+=512) ((short8*)hs)[i]=z; }
    const int b = tid>>5, q = tid&31;
    const int oc = cbase + q*8;
    float cv[8];
#pragma unroll
    for (int j=0;j<8;j++) cv[j]=0.f;
    u32* hr = hring + (size_t)l*1048576;
    u32* pr = pring + (size_t)lv*4194304;
    const int is_last = (l==3);
    __syncthreads();

    for (int t=0;t<1024;++t){
      const u32 tag = (u32)(t+1);
      if (l<3 && (t&15)==0 && t>=32){
        int thr=t-32;
        const int pbase = l*4;
        for(;;){
          int m0=(int)pol32(&prog[pbase]); m0=imin(m0,(int)pol32(&prog[pbase+1]));
          m0=imin(m0,(int)pol32(&prog[pbase+2])); m0=imin(m0,(int)pol32(&prog[pbase+3]));
          if (m0>=thr) break;
          __builtin_amdgcn_s_sleep(8);
        }
      }
      // issue pre poll (first round) so latency hides under the MFMA
      const u32* ps = pr + (size_t)(t&63)*65536 + (size_t)(b0+b)*2048;
      u64 pv[16];
#pragma unroll
      for (int gq=0;gq<4;gq++)
#pragma unroll
        for (int j=0;j<4;j++)
          pv[gq*4+j] = pol64(&ps[gq*512 + oc + 2*j]);
      // recurrent MFMA (needs only hs from t-1)
      f32x4 acc0={0.f,0.f,0.f,0.f}, acc1={0.f,0.f,0.f,0.f};
      {
        int rb=l15*512, sw=(l15&7)<<3;
#pragma unroll
        for (int s=0;s<16;s++){
          short8 a = *(const short8*)&hs[rb + ((s*32+l4*8)^sw)];
          acc0 = __builtin_amdgcn_mfma_f32_16x16x32_bf16(a, bfr[0][s], acc0, 0,0,0);
          acc1 = __builtin_amdgcn_mfma_f32_16x16x32_bf16(a, bfr[1][s], acc1, 0,0,0);
        }
      }
      {
        int base = w*32 + l15;
#pragma unroll
        for (int i=0;i<4;i++){
          recb[(l4*4+i)*256 + base]    = acc0[i];
          recb[(l4*4+i)*256 + base+16] = acc1[i];
        }
      }
      // verify pre poll; on failure gate on pre-cluster flags (forward edge)
      for(;;){
        u32 ok=1;
#pragma unroll
        for (int i=0;i<16;i++){
          if ((u32)(((u32)pv[i])>>16) != tag) ok=0;
          if ((u32)(pv[i]>>48) != tag) ok=0;
        }
        if (ok) break;
        for(;;){
          int mn = 0x7fffffff;
#pragma unroll
          for (int g=0; g<4; g++){
            int cg0 = g*4 + ch*2;
            mn = imin(mn, (int)pol32(&prog[64 + lv*32 + (cg0*2+gb)]));
            mn = imin(mn, (int)pol32(&prog[64 + lv*32 + ((cg0+1)*2+gb)]));
          }
          if (mn >= (int)tag) break;
          __builtin_amdgcn_s_sleep(4);
        }
#pragma unroll
        for (int gq=0;gq<4;gq++)
#pragma unroll
          for (int j=0;j<4;j++)
            pv[gq*4+j] = pol64(&ps[gq*512 + oc + 2*j]);
      }
      barx();
      short8 hvv; float hf[8]; u32 msgw[8];
#pragma unroll
      for (int j=0;j<8;j++){
        float r = recb[b*256 + q*8 + j];
        int wi = j>>1;
        u32 w0 = (j&1) ? (u32)(pv[wi]>>32)    : (u32)pv[wi];
        u32 w1v= (j&1) ? (u32)(pv[4+wi]>>32)  : (u32)pv[4+wi];
        u32 w2 = (j&1) ? (u32)(pv[8+wi]>>32)  : (u32)pv[8+wi];
        u32 w3 = (j&1) ? (u32)(pv[12+wi]>>32) : (u32)pv[12+wi];
        float gi = sigm(bf2f((u16)(w0&0xffffu)) + r);
        float gf = sigm(bf2f((u16)(w1v&0xffffu)) + r);
        float gg = sigm(bf2f((u16)(w2&0xffffu)) + r);
        float go = sigm(bf2f((u16)(w3&0xffffu)) + r);
        cv[j] = gf + cv[j] + gi*gg;
        float h = go + tanh_a(cv[j]);
        u16 hb = f2bf(h);
        hvv[j]=(short)hb; hf[j]=h; msgw[j] = (tag<<16)|(u32)hb;
      }
      u32* hslot = hr + (size_t)(t&63)*16384 + (size_t)(b0+b)*512;
#pragma unroll
      for (int j=0;j<4;j++){
        u64 m = (((u64)msgw[2*j+1])<<32) | (u64)msgw[2*j];
        pub64(&hslot[oc + 2*j], m);
      }
      *(short8*)&hs[b*512 + (oc ^ ((b&7)<<3))] = hvv;
      if (is_last){
        f32x4 h4a={hf[0],hf[1],hf[2],hf[3]}, h4b={hf[4],hf[5],hf[6],hf[7]};
        *(f32x4*)&out[32768 + ((size_t)((b0+b)*1024+t))*512 + oc]   = h4a;
        *(f32x4*)&out[32768 + ((size_t)((b0+b)*1024+t))*512 + oc+4] = h4b;
        if (t==1023){
          *(f32x4*)&out[(size_t)(b0+b)*512 + oc]   = h4a;
          *(f32x4*)&out[(size_t)(b0+b)*512 + oc+4] = h4b;
          f32x4 c4a={cv[0],cv[1],cv[2],cv[3]}, c4b={cv[4],cv[5],cv[6],cv[7]};
          *(f32x4*)&out[16384 + (size_t)(b0+b)*512 + oc]   = c4a;
          *(f32x4*)&out[16384 + (size_t)(b0+b)*512 + oc+4] = c4b;
        }
      }
      // partner gather (cyclic edge: pure tag-poll)
      {
        const u32* src = hslot + (ch^1)*256 + q*8;
        u64 nv[4];
        for(;;){
#pragma unroll
          for (int j=0;j<4;j++) nv[j] = pol64(&src[2*j]);
          u32 ok=1;
#pragma unroll
          for (int j=0;j<4;j++){
            if ((u32)(((u32)nv[j])>>16)!=tag) ok=0;
            if ((u32)(nv[j]>>48)!=tag) ok=0;
          }
          if (ok) break;
          __builtin_amdgcn_s_sleep(1);
        }
        short8 hh;
#pragma unroll
        for (int j=0;j<4;j++){
          hh[2*j]   = (short)(u16)(nv[j] & 0xffffu);
          hh[2*j+1] = (short)(u16)((nv[j]>>32) & 0xffffu);
        }
        int pc = (ch^1)*256 + q*8;
        *(short8*)&hs[b*512 + (pc ^ ((b&7)<<3))] = hh;
      }
      barx();
      if (tid==0) pub32(&prog[(l-1)*4 + sub], (u32)(t+1));
    }
  } else {
    // ======== pre clusters: rec-pre[t] = [x[t] : h_prev[t]] @ [wx;wh]^T + b0 ========
    u16* hstage = (u16*)smem;
    const int idx = bid - 28;
    const int lv = idx >> 5;
    const int r  = idx & 31;
    const int gb = r & 1, cg = r >> 1;
    const int b0 = gb*16;
    const int c  = cg*128 + w*16 + l15;
    const u16* Bw = wxwhp + (size_t)lv*2097152 + (size_t)c*1024;
    short8 bfr[32];
#pragma unroll
    for (int s=0;s<32;s++) bfr[s] = *(const short8*)&Bw[s*32 + l4*8];
    const float bias = bv[lv*2048 + (c & 511)];
    const int prow_ = tid >> 5;
    const int px = tid & 31;
    const u32* hrb = hring + (size_t)lv*1048576;
    u32* prb = pring + (size_t)lv*4194304;

    for (int t=0;t<1024;++t){
      const u32 tag = (u32)(t+1);
      // 1) issue h poll (first round)
      const u32* hsrc = hrb + (size_t)(t&63)*16384 + (size_t)(b0+prow_)*512;
      u64 nv[8];
#pragma unroll
      for (int j=0;j<8;j++) nv[j] = pol64(&hsrc[px*2 + 64*j]);
      // 2) x-part MFMA overlaps the poll latency (xb [t][b][512] -> L3-hot)
      f32x4 acc = {0.f,0.f,0.f,0.f};
      const u16* xrow = xb + (size_t)(t*32 + b0 + l15)*512;
#pragma unroll
      for (int s=0;s<16;s++){
        short8 a = *(const short8*)&xrow[s*32 + l4*8];
        acc = __builtin_amdgcn_mfma_f32_16x16x32_bf16(a, bfr[s], acc, 0,0,0);
      }
      // 3) verify; on failure gate on producer flags (forward edge), then re-read
      for(;;){
        u32 ok=1;
#pragma unroll
        for (int j=0;j<8;j++){
          if ((u32)(((u32)nv[j])>>16)!=tag) ok=0;
          if ((u32)(nv[j]>>48)!=tag) ok=0;
        }
        if (ok) break;
        if (lv==0){
          for(;;){
            int mn = 0x7fffffff;
#pragma unroll
            for (int j=0;j<8;j++) mn = imin(mn, (int)pol32(&prog[32 + gb*8 + j]));
            if (mn >= (int)tag) break;
            __builtin_amdgcn_s_sleep(4);
          }
        } else {
          for(;;){
            int a2 = (int)pol32(&prog[(lv-1)*4 + gb*2]);
            int c2 = (int)pol32(&prog[(lv-1)*4 + gb*2 + 1]);
            if (imin(a2,c2) >= (int)tag) break;
            __builtin_amdgcn_s_sleep(4);
          }
        }
#pragma unroll
        for (int j=0;j<8;j++) nv[j] = pol64(&hsrc[px*2 + 64*j]);
      }
      // 4) stage h to LDS (pad-520 keeps banks clean)
#pragma unroll
      for (int j=0;j<8;j++){
        u32 pair = ((u32)nv[j]&0xffffu) | ((u32)((nv[j]>>32)&0xffffu)<<16);
        *(u32*)&hstage[prow_*520 + px*2 + 64*j] = pair;
      }
      barx();
      // 5) h-part MFMA
#pragma unroll
      for (int s=0;s<16;s++){
        short8 a = *(const short8*)&hstage[l15*520 + s*32 + l4*8];
        acc = __builtin_amdgcn_mfma_f32_16x16x32_bf16(a, bfr[16+s], acc, 0,0,0);
      }
      // 6) publish tagged pre
      u32* dst = prb + (size_t)(t&63)*65536 + c;
#pragma unroll
      for (int i=0;i<4;i++){
        u32 v = ((u32)f2bf(acc[i]+bias)) | (tag<<16);
        pub32(&dst[(size_t)(b0 + l4*4 + i)*2048], v);
      }
      barx();
      if (tid==0) pub32(&prog[64 + lv*32 + r], (u32)(t+1));
    }
  }
}

extern "C" void kernel_launch(void* const* d_in, const int* in_sizes, int n_in,
                              void* d_out, int out_size, void* d_ws, size_t ws_size,
                              hipStream_t stream)
{
  const float* x  = (const float*)d_in[0];
  const float* w1 = (const float*)d_in[1];
  const float* u1 = (const float*)d_in[2];
  const float* b1 = (const float*)d_in[3];
  const float* wx = (const float*)d_in[4];
  const float* wh = (const float*)d_in[5];
  const float* uv = (const float*)d_in[6];
  const float* bv = (const float*)d_in[7];
  float* out = (float*)d_out;

  char* p = (char*)d_ws;
  u16* pre1  = (u16*)p; p += (size_t)134217728;  // [1024*32][2048] bf16, rows t*32+b
  u16* xb    = (u16*)p; p += 33554432;           // [1024][32][512] bf16
  u16* w1p   = (u16*)p; p += 2097152;
  u16* wxwhp = (u16*)p; p += 12582912;           // 3 x [2048][1024] bf16
  u16* u1p   = (u16*)p; p += 2097152;
  u16* uv0p  = (u16*)p; p += 1572864;
  u32* hring = (u32*)p; p += 16777216;           // 4 x [64][32][512] u32
  u32* pring = (u32*)p; p += 50331648;           // 3 x [64][32][2048] u32
  u32* prog  = (u32*)p; p += 1024;
  if ((size_t)(p - (char*)d_ws) > ws_size) return;

  hipMemsetAsync(hring, 0, 16777216, stream);
  hipMemsetAsync(pring, 0, 50331648, stream);
  hipMemsetAsync(prog, 0, 1024, stream);
  cast_x_kernel<<<2048,256,0,stream>>>(x, xb);
  pack_w_kernel<<<2048,256,0,stream>>>(w1, wx, wh, w1p, wxwhp);
  cast_u_kernel<<<1024,256,0,stream>>>(u1, uv, u1p, uv0p);

  gemm_pre_kernel<<<dim3(256,16),256,0,stream>>>(xb, w1p, b1, 2047, pre1);
  mega_kernel<<<124,512,0,stream>>>(pre1, u1p, uv0p, xb, wxwhp, bv, hring, pring, prog, out);
}